// Round 3
// baseline (124.732 us; speedup 1.0000x reference)
//
#include <hip/hip_runtime.h>
#include <math.h>

// Problem constants (from reference)
#define NCAMS 48      // B*NC = 8*6
#define NC_   6
#define A_    25200
#define C_    10
#define MAXGT 32
#define L_COORD 5.0f
#define L_NOOBJ 0.5f

// Decomposition: 4 anchors per thread -> 1200 blocks, ~19 waves/CU.
// One ds_read_b128 of a GT box serves 4 IoU evaluations.
#define BLOCK  256
#define APT    4
#define CHUNK  (BLOCK * APT)                 // 1024 anchors per block
#define NCHUNK ((A_ + CHUNK - 1) / CHUNK)    // 25

__device__ __forceinline__ float softplus_f(float x) {
    return fmaxf(x, 0.0f) + log1pf(expf(-fabsf(x)));
}

// Phase 1: per (cam, anchor-chunk) block -> 6 partial sums
__global__ __launch_bounds__(BLOCK)
void yolo_phase1(const float* __restrict__ pred_boxes,   // (cams, A, 4)
                 const float* __restrict__ pred_labels,  // (cams, A, C)
                 const float* __restrict__ pred_obj,     // (cams, A, 1)
                 const float* __restrict__ gt_boxes,     // (TG, 4) cxcywh
                 const int*   __restrict__ gt_labels,    // (TG)
                 const int*   __restrict__ se,           // (B, NC)
                 int total_gt,
                 float* __restrict__ partials)           // (cams*NCHUNK, 8)
{
    const int cam   = blockIdx.y;
    const int chunk = blockIdx.x;
    const int tid   = threadIdx.x;

    __shared__ float4 s_corner[MAXGT];   // g1x, g1y, g2x, g2y
    __shared__ float4 s_orig[MAXGT];     // cx, cy, w, h (exact, rare pos path)
    __shared__ float  s_area[MAXGT];     // LDS pipe is idle vs VALU: keep here
    __shared__ int    s_lbl[MAXGT];
    __shared__ float  s_red[BLOCK / 64][6];

    const int b  = cam / NC_;
    const int nc = cam - b * NC_;
    int off = 0;
    for (int bb = 0; bb < b; ++bb) off += se[bb * NC_ + (NC_ - 1)];
    const int start = off + (nc ? se[b * NC_ + nc - 1] : 0);
    const int end   = off + se[b * NC_ + nc];
    int ngt = end - start;
    if (ngt < 0) ngt = 0;
    if (ngt > MAXGT) ngt = MAXGT;

    if (tid < ngt) {
        int gi = start + tid;
        gi = min(max(gi, 0), total_gt - 1);   // reference clips gidx
        float4 gb = ((const float4*)gt_boxes)[gi];
        float hw = gb.z * 0.5f, hh = gb.w * 0.5f;
        s_corner[tid] = make_float4(gb.x - hw, gb.y - hh, gb.x + hw, gb.y + hh);
        s_orig[tid]   = gb;
        s_area[tid]   = gb.z * gb.w;
        s_lbl[tid]    = gt_labels[gi];
    }
    __syncthreads();

    const int base = chunk * CHUNK;
    const float4* pb4 = (const float4*)pred_boxes;

    int   aidx[APT];
    bool  valid[APT];
    float p1x[APT], p1y[APT], p2x[APT], p2y[APT], pa[APT];
    float bn[APT], bd[APT];   // best iou as fraction bn/bd (bd>0)
    int   bk[APT];
    float o[APT];
    float4 p[APT];

    #pragma unroll
    for (int j = 0; j < APT; ++j) {
        const int a = base + j * BLOCK + tid;
        valid[j] = (a < A_);
        const int ac = valid[j] ? a : (A_ - 1);
        const int idx = cam * A_ + ac;            // < 1.21M, fits int
        aidx[j] = idx;
        p[j] = pb4[idx];
        o[j] = pred_obj[idx];
        const float hw = p[j].z * 0.5f, hh = p[j].w * 0.5f;
        p1x[j] = p[j].x - hw; p1y[j] = p[j].y - hh;
        p2x[j] = p[j].x + hw; p2y[j] = p[j].y + hh;
        pa[j]  = p[j].z * p[j].w + 1e-6f;         // fold +1e-6 into denom
        bn[j] = -1.0f; bd[j] = 1.0f; bk[j] = 0;
    }

    // argmax IoU via cross-multiply: inter/d > bn/bd  <=>  inter*bd > bn*d
    // (d,bd > 0). No division/rcp in the hot loop. Strict '>' ascending k
    // == jnp.argmax first-max semantics.
    auto iou_step = [&](int k) {
        const float4 g = s_corner[k];
        const float ga = s_area[k];
        #pragma unroll
        for (int j = 0; j < APT; ++j) {
            const float wx = fmaxf(fminf(p2x[j], g.z) - fmaxf(p1x[j], g.x), 0.0f);
            const float wy = fmaxf(fminf(p2y[j], g.w) - fmaxf(p1y[j], g.y), 0.0f);
            const float inter = wx * wy;
            const float d = pa[j] + (ga - inter);
            const bool better = inter * bd[j] > bn[j] * d;
            bn[j] = better ? inter : bn[j];
            bd[j] = better ? d     : bd[j];
            bk[j] = better ? k     : bk[j];
        }
    };

    if (ngt == 20) {                 // hot path in this dataset: full unroll
        #pragma unroll
        for (int k = 0; k < 20; ++k) iou_step(k);
    } else {
        for (int k = 0; k < ngt; ++k) iou_step(k);
    }

    float pos_cnt = 0.f, neg_cnt = 0.f;
    float box_acc = 0.f, spp_acc = 0.f, spn_acc = 0.f, ce_acc = 0.f;

    #pragma unroll
    for (int j = 0; j < APT; ++j) {
        if (!valid[j]) continue;
        // best_iou > 0.5  <=>  bn > 0.5*bd  (ngt==0 -> bn=-1 -> false)
        if (bn[j] > 0.5f * bd[j]) {
            pos_cnt += 1.0f;
            const float4 mb = s_orig[bk[j]];
            const float dx = p[j].x - mb.x, dy = p[j].y - mb.y;
            const float dz = p[j].z - mb.z, dw = p[j].w - mb.w;
            box_acc += dx * dx + dy * dy + dz * dz + dw * dw;
            spp_acc += softplus_f(-o[j]);
            const float* lg = pred_labels + aidx[j] * C_;  // rare path
            float m = lg[0];
            #pragma unroll
            for (int i = 1; i < C_; ++i) m = fmaxf(m, lg[i]);
            float sexp = 0.f;
            #pragma unroll
            for (int i = 0; i < C_; ++i) sexp += expf(lg[i] - m);
            ce_acc += -(lg[s_lbl[bk[j]]] - m - logf(sexp));
        } else {
            neg_cnt += 1.0f;
            spn_acc += softplus_f(o[j]);
        }
    }

    // block reduction of 6 values
    float v[6] = {pos_cnt, neg_cnt, box_acc, spp_acc, spn_acc, ce_acc};
    #pragma unroll
    for (int i = 0; i < 6; ++i) {
        float x = v[i];
        for (int s = 32; s; s >>= 1) x += __shfl_down(x, s, 64);
        v[i] = x;
    }
    if ((tid & 63) == 0) {
        const int w = tid >> 6;
        #pragma unroll
        for (int i = 0; i < 6; ++i) s_red[w][i] = v[i];
    }
    __syncthreads();
    if (tid == 0) {
        float* outp = partials + (size_t)(cam * NCHUNK + chunk) * 8;
        #pragma unroll
        for (int i = 0; i < 6; ++i)
            outp[i] = s_red[0][i] + s_red[1][i] + s_red[2][i] + s_red[3][i];
    }
}

// Phase 2: one wave combines all partials with reference semantics.
__global__ void yolo_phase2(const float* __restrict__ partials,
                            float* __restrict__ out)
{
    const int t = threadIdx.x;   // 0..63
    float box_sum = 0.f, obj_sum = 0.f, noobj_sum = 0.f, cls_sum = 0.f;
    float np_ = 0.f, nn_ = 0.f;

    if (t < NCAMS) {
        float pp = 0.f, n = 0.f, bx = 0.f, sp = 0.f, sn = 0.f, ce = 0.f;
        for (int h = 0; h < NCHUNK; ++h) {
            const float* q = partials + (size_t)(t * NCHUNK + h) * 8;
            pp += q[0]; n  += q[1]; bx += q[2];
            sp += q[3]; sn += q[4]; ce += q[5];
        }
        box_sum   = L_COORD * bx;
        obj_sum   = (pp > 0.f) ? sp / fmaxf(pp, 1.0f) : 0.f;
        cls_sum   = (pp > 0.f) ? ce / fmaxf(pp, 1.0f) : 0.f;
        noobj_sum = L_NOOBJ * ((n > 0.f) ? sn / fmaxf(n, 1.0f) : 0.f);
        np_ = pp; nn_ = n;
    }
    for (int s = 32; s; s >>= 1) {
        box_sum   += __shfl_down(box_sum, s, 64);
        obj_sum   += __shfl_down(obj_sum, s, 64);
        noobj_sum += __shfl_down(noobj_sum, s, 64);
        cls_sum   += __shfl_down(cls_sum, s, 64);
        np_       += __shfl_down(np_, s, 64);
        nn_       += __shfl_down(nn_, s, 64);
    }
    if (t == 0) {
        const float box_loss   = (np_ > 0.f) ? box_sum / fmaxf(np_, 1.0f) : 0.f;
        const float obj_loss   = (np_ > 0.f) ? obj_sum / fmaxf(np_, 1.0f) : 0.f;
        const float cls_loss   = (np_ > 0.f) ? cls_sum / fmaxf(np_, 1.0f) : 0.f;
        const float noobj_loss = (nn_ > 0.f) ? noobj_sum / fmaxf(nn_, 1.0f) : 0.f;
        const float total = box_loss + obj_loss + noobj_loss + cls_loss;
        out[0] = total;
        out[1] = box_loss;
        out[2] = obj_loss;
        out[3] = noobj_loss;
        out[4] = cls_loss;
    }
}

extern "C" void kernel_launch(void* const* d_in, const int* in_sizes, int n_in,
                              void* d_out, int out_size, void* d_ws, size_t ws_size,
                              hipStream_t stream) {
    const float* pred_boxes  = (const float*)d_in[0];
    const float* pred_labels = (const float*)d_in[1];
    const float* pred_obj    = (const float*)d_in[2];
    const float* gt_boxes    = (const float*)d_in[3];
    const int*   gt_labels   = (const int*)d_in[4];
    const int*   se          = (const int*)d_in[5];
    const int total_gt = in_sizes[3] / 4;

    float* partials = (float*)d_ws;   // NCAMS*NCHUNK*8 floats = 37.5 KB

    dim3 grid(NCHUNK, NCAMS);
    yolo_phase1<<<grid, BLOCK, 0, stream>>>(pred_boxes, pred_labels, pred_obj,
                                            gt_boxes, gt_labels, se,
                                            total_gt, partials);
    yolo_phase2<<<1, 64, 0, stream>>>(partials, (float*)d_out);
}